// Round 2
// baseline (365.247 us; speedup 1.0000x reference)
//
#include <hip/hip_runtime.h>

// Problem constants (GATConv_17635135717523)
// N=50000 nodes, E=800000 edges, IN=256, H=8, O=32, H*O=256
#define N_NODES 50000
#define N_EDGES 800000
#define NPAD    50176   // 196*256

typedef __bf16 bf16x8 __attribute__((ext_vector_type(8)));
typedef float  fx4    __attribute__((ext_vector_type(4)));
typedef unsigned short us4 __attribute__((ext_vector_type(4)));

__device__ __forceinline__ float b2f(unsigned short u) {
    return __uint_as_float(((unsigned)u) << 16);
}
__device__ __forceinline__ unsigned short f2b(float f) {
    unsigned x = __float_as_uint(f);
    return (unsigned short)((x + 0x7FFFu + ((x >> 16) & 1u)) >> 16);
}

// ------------------------------------------------------- feat fp32 -> bf16
__global__ __launch_bounds__(256) void cvt_feat(
    const float* __restrict__ feat, unsigned short* __restrict__ featb) {
    int t = blockIdx.x * 256 + threadIdx.x;   // 3.2M threads, 4 elems each
    float4 v = reinterpret_cast<const float4*>(feat)[t];
    us4 o;
    o.x = f2b(v.x); o.y = f2b(v.y); o.z = f2b(v.z); o.w = f2b(v.w);
    reinterpret_cast<us4*>(featb)[t] = o;
}

// ------------------------------------------------------- W fp32 -> Wt hi/lo
// Wt_hi[n][k] + Wt_lo[n][k] ~= W[k][n] to ~2^-18 rel. n-major so k contiguous.
__global__ __launch_bounds__(256) void transpose_w(
    const float* __restrict__ W,
    unsigned short* __restrict__ Wt_hi, unsigned short* __restrict__ Wt_lo) {
    int n = blockIdx.x, k = threadIdx.x;
    float w = W[k * 256 + n];
    unsigned short h = f2b(w);
    Wt_hi[n * 256 + k] = h;
    Wt_lo[n * 256 + k] = f2b(w - b2f(h));
}

// ------------------------------------------------------- GEMM ft = feat @ W
// featb [N,256] bf16 row-major; Wt_hi/lo [256,256] bf16 n-major.
// 128x128 tile / block, 4 waves 2x2, each wave 4x4 frags of 16x16x32.
// Two MFMA passes (B_hi, B_lo) recover fp32-accurate W.
__global__ __launch_bounds__(256) void gemm_ft(
    const unsigned short* __restrict__ featb,
    const unsigned short* __restrict__ Wt_hi,
    const unsigned short* __restrict__ Wt_lo,
    unsigned short* __restrict__ ft) {
    const int tid  = threadIdx.x;
    const int lane = tid & 63;
    const int wid  = tid >> 6;
    const int wm   = wid & 1, wn = wid >> 1;
    const int quad = lane >> 4, l15 = lane & 15;
    const int mbase = blockIdx.x * 128 + wm * 64;
    const int nbase = blockIdx.y * 128 + wn * 64;

    fx4 acc[4][4];
#pragma unroll
    for (int i = 0; i < 4; ++i)
#pragma unroll
        for (int j = 0; j < 4; ++j) acc[i][j] = (fx4)0.0f;

#pragma unroll 2
    for (int k0 = 0; k0 < 256; k0 += 32) {
        const int krow = k0 + quad * 8;
        bf16x8 a[4], bh[4], bl[4];
#pragma unroll
        for (int mt = 0; mt < 4; ++mt) {
            int m = mbase + mt * 16 + l15;
            m = m < N_NODES ? m : N_NODES - 1;
            a[mt] = *reinterpret_cast<const bf16x8*>(featb + (size_t)m * 256 + krow);
        }
#pragma unroll
        for (int nt = 0; nt < 4; ++nt) {
            int n = nbase + nt * 16 + l15;
            bh[nt] = *reinterpret_cast<const bf16x8*>(Wt_hi + n * 256 + krow);
            bl[nt] = *reinterpret_cast<const bf16x8*>(Wt_lo + n * 256 + krow);
        }
#pragma unroll
        for (int mt = 0; mt < 4; ++mt)
#pragma unroll
            for (int nt = 0; nt < 4; ++nt) {
                acc[mt][nt] = __builtin_amdgcn_mfma_f32_16x16x32_bf16(
                    a[mt], bh[nt], acc[mt][nt], 0, 0, 0);
                acc[mt][nt] = __builtin_amdgcn_mfma_f32_16x16x32_bf16(
                    a[mt], bl[nt], acc[mt][nt], 0, 0, 0);
            }
    }

    // C/D layout: col = lane&15, row = (lane>>4)*4 + reg  [verified m89/m91]
#pragma unroll
    for (int mt = 0; mt < 4; ++mt) {
#pragma unroll
        for (int r = 0; r < 4; ++r) {
            int row = mbase + mt * 16 + quad * 4 + r;
            if (row < N_NODES) {
#pragma unroll
                for (int nt = 0; nt < 4; ++nt) {
                    int col = nbase + nt * 16 + l15;
                    ft[(size_t)row * 256 + col] = f2b(acc[mt][nt][r]);
                }
            }
        }
    }
}

// ------------------------------------------------------- el/er logits
// One wave per node; lane owns 4 of 256 elems; 8 lanes per head.
__global__ __launch_bounds__(256) void node_logits(
    const unsigned short* __restrict__ ft,
    const float* __restrict__ attn_l,
    const float* __restrict__ attn_r,
    float* __restrict__ el, float* __restrict__ er) {
    int wid = threadIdx.x >> 6, lane = threadIdx.x & 63;
    int v = blockIdx.x * 4 + wid;
    if (v >= N_NODES) return;
    us4 f = *reinterpret_cast<const us4*>(ft + (size_t)v * 256 + lane * 4);
    float4 al = reinterpret_cast<const float4*>(attn_l)[lane];
    float4 ar = reinterpret_cast<const float4*>(attn_r)[lane];
    float pl = 0.f, pr = 0.f;
    float x0 = b2f(f.x), x1 = b2f(f.y), x2 = b2f(f.z), x3 = b2f(f.w);
    pl = x0 * al.x + x1 * al.y + x2 * al.z + x3 * al.w;
    pr = x0 * ar.x + x1 * ar.y + x2 * ar.z + x3 * ar.w;
    pl += __shfl_xor(pl, 1); pr += __shfl_xor(pr, 1);
    pl += __shfl_xor(pl, 2); pr += __shfl_xor(pr, 2);
    pl += __shfl_xor(pl, 4); pr += __shfl_xor(pr, 4);
    if ((lane & 7) == 0) {
        int h = lane >> 3;
        el[v * 8 + h] = pl;
        er[v * 8 + h] = pr;
    }
}

// ------------------------------------------------------- CSR build
__global__ __launch_bounds__(256) void count_deg(
    const int* __restrict__ dst, int* __restrict__ cnt) {
    int t = blockIdx.x * 256 + threadIdx.x;
    if (t < N_EDGES) atomicAdd(&cnt[dst[t]], 1);
}

__global__ __launch_bounds__(256) void block_sum(
    const int* __restrict__ cnt, int* __restrict__ bsum) {
    int i = blockIdx.x * 256 + threadIdx.x;
    int v = cnt[i];
#pragma unroll
    for (int off = 1; off < 64; off <<= 1) v += __shfl_xor(v, off);
    __shared__ int s[4];
    if ((threadIdx.x & 63) == 0) s[threadIdx.x >> 6] = v;
    __syncthreads();
    if (threadIdx.x == 0) bsum[blockIdx.x] = s[0] + s[1] + s[2] + s[3];
}

__global__ __launch_bounds__(256) void block_scan(
    const int* __restrict__ bsum, int* __restrict__ boff) {
    __shared__ int s[256];
    int t = threadIdx.x;
    int v = (t < 196) ? bsum[t] : 0;
    s[t] = v;
    __syncthreads();
    for (int off = 1; off < 256; off <<= 1) {
        int add = (t >= off) ? s[t - off] : 0;
        __syncthreads();
        s[t] += add;
        __syncthreads();
    }
    if (t < 196) boff[t] = s[t] - v;   // exclusive
}

__global__ __launch_bounds__(256) void scan_offsets(
    const int* __restrict__ cnt, const int* __restrict__ boff,
    int* __restrict__ off, int* __restrict__ cursor) {
    int t = threadIdx.x, lane = t & 63, wid = t >> 6;
    int i = blockIdx.x * 256 + t;
    int c = cnt[i];
    int x = c;
#pragma unroll
    for (int d = 1; d < 64; d <<= 1) {
        int y = __shfl_up(x, d);
        if (lane >= d) x += y;
    }
    __shared__ int wt[4];
    if (lane == 63) wt[wid] = x;
    __syncthreads();
    int woff = 0;
    for (int w = 0; w < wid; ++w) woff += wt[w];
    int excl = boff[blockIdx.x] + woff + x - c;
    off[i] = excl;
    cursor[i] = excl;
}

__global__ __launch_bounds__(256) void bucket_edges(
    const int* __restrict__ src, const int* __restrict__ dst,
    int* __restrict__ cursor, int* __restrict__ inedge_src) {
    int t = blockIdx.x * 256 + threadIdx.x;
    if (t < N_EDGES) {
        int d = dst[t];
        int p = atomicAdd(&cursor[d], 1);
        inedge_src[p] = src[t];
    }
}

// ------------------------------------------------------- aggregation
// One wave per dst node. Softmax without max-subtraction (|logit| ~ O(1);
// exp(e)/sum(exp(e)) is mathematically identical to the stabilized form).
__global__ __launch_bounds__(256) void aggregate(
    const unsigned short* __restrict__ ft,
    const float* __restrict__ el, const float* __restrict__ er,
    const int* __restrict__ off, const int* __restrict__ cnt,
    const int* __restrict__ inedge_src,
    const float* __restrict__ bias,
    float* __restrict__ out) {
    int wid = threadIdx.x >> 6, lane = threadIdx.x & 63;
    int v = blockIdx.x * 4 + wid;
    if (v >= N_NODES) return;
    int start = off[v], deg = cnt[v];
    int h1 = lane & 7;    // phase B: lane = (edge_local<<3) | head
    int h2 = lane >> 3;   // phase C: lane owns out elems [lane*4, lane*4+4)
    float er1 = er[v * 8 + h1];
    float er2 = er[v * 8 + h2];

    // Phase B: softmax denominator per head
    float s = 0.f;
    for (int base = 0; base < deg; base += 8) {
        int e = base + (lane >> 3);
        if (e < deg) {
            int u = inedge_src[start + e];
            float w = el[u * 8 + h1] + er1;
            w = w > 0.f ? w : 0.2f * w;
            s += __expf(w);
        }
    }
    s += __shfl_xor(s, 8);
    s += __shfl_xor(s, 16);
    s += __shfl_xor(s, 32);
    float sv = __shfl(s, h2);           // denom for this lane's head
    float inv = deg > 0 ? 1.0f / sv : 0.f;

    // Phase C: weighted gather-sum
    float a0 = 0.f, a1 = 0.f, a2 = 0.f, a3 = 0.f;
    for (int j = 0; j < deg; ++j) {
        int u = inedge_src[start + j];
        float w = el[u * 8 + h2] + er2;
        w = w > 0.f ? w : 0.2f * w;
        float a = __expf(w) * inv;
        us4 f = *reinterpret_cast<const us4*>(ft + (size_t)u * 256 + lane * 4);
        a0 += a * b2f(f.x);
        a1 += a * b2f(f.y);
        a2 += a * b2f(f.z);
        a3 += a * b2f(f.w);
    }
    float4 bb = reinterpret_cast<const float4*>(bias)[lane];
    float4 o;
    o.x = a0 + bb.x; o.y = a1 + bb.y; o.z = a2 + bb.z; o.w = a3 + bb.w;
    reinterpret_cast<float4*>(out)[(size_t)v * 64 + lane] = o;
}

// ------------------------------------------------------- launch
extern "C" void kernel_launch(void* const* d_in, const int* in_sizes, int n_in,
                              void* d_out, int out_size, void* d_ws, size_t ws_size,
                              hipStream_t stream) {
    const float* feat   = (const float*)d_in[0];
    const float* W      = (const float*)d_in[1];
    const float* attn_l = (const float*)d_in[2];
    const float* attn_r = (const float*)d_in[3];
    const float* bias   = (const float*)d_in[4];
    const int* src = (const int*)d_in[5];
    const int* dst = (const int*)d_in[6];
    float* out = (float*)d_out;

    char* ws = (char*)d_ws;
    // workspace layout (16B aligned), ~58.5 MB total
    unsigned short* Wt_hi = (unsigned short*)(ws + 0);          //    131,072
    unsigned short* Wt_lo = (unsigned short*)(ws + 131072);     //    131,072
    unsigned short* featb = (unsigned short*)(ws + 262144);     // 25,600,000
    unsigned short* ft    = (unsigned short*)(ws + 25862144);   // 25,600,000
    float* el             = (float*)(ws + 51462144);            //  1,600,000
    float* er             = (float*)(ws + 53062144);            //  1,600,000
    int* cnt              = (int*)(ws + 54662144);              //    200,704
    int* off              = (int*)(ws + 54862848);              //    200,704
    int* cursor           = (int*)(ws + 55063552);              //    200,704
    int* bsum             = (int*)(ws + 55264256);              //      1,024
    int* boff             = (int*)(ws + 55265280);              //      1,024
    int* inedge_src       = (int*)(ws + 55266304);              //  3,200,000

    hipMemsetAsync(cnt, 0, NPAD * sizeof(int), stream);

    cvt_feat<<<12500, 256, 0, stream>>>(feat, featb);
    transpose_w<<<256, 256, 0, stream>>>(W, Wt_hi, Wt_lo);
    gemm_ft<<<dim3(391, 2), 256, 0, stream>>>(featb, Wt_hi, Wt_lo, ft);
    node_logits<<<12500, 256, 0, stream>>>(ft, attn_l, attn_r, el, er);
    count_deg<<<3125, 256, 0, stream>>>(dst, cnt);
    block_sum<<<196, 256, 0, stream>>>(cnt, bsum);
    block_scan<<<1, 256, 0, stream>>>(bsum, boff);
    scan_offsets<<<196, 256, 0, stream>>>(cnt, boff, off, cursor);
    bucket_edges<<<3125, 256, 0, stream>>>(src, dst, cursor, inedge_src);
    aggregate<<<12500, 256, 0, stream>>>(ft, el, er, off, cnt, inedge_src, bias, out);
}

// Round 3
// 298.952 us; speedup vs baseline: 1.2218x; 1.2218x over previous
//
#include <hip/hip_runtime.h>

// Problem constants (GATConv_17635135717523)
// N=50000 nodes, E=800000 edges, IN=256, H=8, O=32, H*O=256
#define N_NODES 50000
#define N_EDGES 800000
#define NPAD    50176   // 196*256
#define MAXD    96      // LDS expw stash depth per node (P(deg>96) ~ 0)

typedef __bf16 bf16x8 __attribute__((ext_vector_type(8)));
typedef float  fx4    __attribute__((ext_vector_type(4)));
typedef unsigned short us4 __attribute__((ext_vector_type(4)));
typedef unsigned short us8 __attribute__((ext_vector_type(8)));

__device__ __forceinline__ float b2f(unsigned short u) {
    return __uint_as_float(((unsigned)u) << 16);
}
__device__ __forceinline__ unsigned short f2b(float f) {
    unsigned x = __float_as_uint(f);
    return (unsigned short)((x + 0x7FFFu + ((x >> 16) & 1u)) >> 16);
}

// ------------------------------------------------------- W fp32 -> Wt bf16 (hi only)
// Wt[n][k] = bf16(W[k][n]); n-major so k contiguous for B fragments.
__global__ __launch_bounds__(256) void transpose_w(
    const float* __restrict__ W, unsigned short* __restrict__ Wt) {
    int n = blockIdx.x, k = threadIdx.x;
    Wt[n * 256 + k] = f2b(W[k * 256 + n]);
}

// ------------------------------------------------------- M2 = per-head (W . attn)
// M2t[j][k], j in [0,16): j<8 -> el head j, j>=8 -> er head j-8.
// M2[k][j] = sum_{o<32} W[k][ (j&7)*32+o ] * attn[(j&7)*32+o]. Stored hi+lo bf16.
__global__ __launch_bounds__(256) void prep_m2(
    const float* __restrict__ W,
    const float* __restrict__ attn_l, const float* __restrict__ attn_r,
    unsigned short* __restrict__ M2t_hi, unsigned short* __restrict__ M2t_lo) {
    int j = blockIdx.x, k = threadIdx.x;
    const float* av = (j < 8) ? (attn_l + j * 32) : (attn_r + (j - 8) * 32);
    int c0 = (j & 7) * 32;
    float s = 0.f;
#pragma unroll
    for (int o = 0; o < 32; ++o) s += W[k * 256 + c0 + o] * av[o];
    unsigned short h = f2b(s);
    M2t_hi[j * 256 + k] = h;
    M2t_lo[j * 256 + k] = f2b(s - b2f(h));
}

// ------------------------------------------------------- fused GEMM
// ft = bf16(feat @ W); el/er = feat @ M2 (fp32 out).
// Block: 64 rows x 256 cols. 4 waves; wave w owns cols [w*64, w*64+64).
// feat fp32 staged -> bf16 LDS tile [64][40] (pad 32->40, 2-way-free banks).
// Wave 0 additionally computes the 16-col el/er fragment (M2 hi+lo).
__global__ __launch_bounds__(256) void gemm_ft(
    const float* __restrict__ feat,
    const unsigned short* __restrict__ Wt,
    const unsigned short* __restrict__ M2t_hi,
    const unsigned short* __restrict__ M2t_lo,
    unsigned short* __restrict__ ft,
    float* __restrict__ el, float* __restrict__ er) {
    __shared__ unsigned short Alds[64 * 40];
    const int tid  = threadIdx.x;
    const int lane = tid & 63;
    const int wid  = tid >> 6;
    const int quad = lane >> 4, l15 = lane & 15;
    const int mbase = blockIdx.x * 64;
    const int nbase = wid * 64;

    fx4 acc[4][4];
    fx4 acce[4];
#pragma unroll
    for (int i = 0; i < 4; ++i) {
        acce[i] = (fx4)0.0f;
#pragma unroll
        for (int j = 0; j < 4; ++j) acc[i][j] = (fx4)0.0f;
    }

    // staging role: thread -> (row, 8-elem k segment)
    const int srow  = tid >> 2;
    const int skseg = (tid & 3) * 8;
    int grow = mbase + srow;
    grow = grow < N_NODES ? grow : N_NODES - 1;
    const float* sp = feat + (size_t)grow * 256 + skseg;
    unsigned short* sdst = &Alds[srow * 40 + skseg];

    for (int k0 = 0; k0 < 256; k0 += 32) {
        __syncthreads();
        float4 f0 = *reinterpret_cast<const float4*>(sp + k0);
        float4 f1 = *reinterpret_cast<const float4*>(sp + k0 + 4);
        us8 pk;
        pk[0] = f2b(f0.x); pk[1] = f2b(f0.y); pk[2] = f2b(f0.z); pk[3] = f2b(f0.w);
        pk[4] = f2b(f1.x); pk[5] = f2b(f1.y); pk[6] = f2b(f1.z); pk[7] = f2b(f1.w);
        *reinterpret_cast<us8*>(sdst) = pk;
        __syncthreads();

        const int krow = k0 + quad * 8;
        bf16x8 a[4], b[4];
#pragma unroll
        for (int mt = 0; mt < 4; ++mt)
            a[mt] = *reinterpret_cast<const bf16x8*>(&Alds[(mt * 16 + l15) * 40 + quad * 8]);
#pragma unroll
        for (int nt = 0; nt < 4; ++nt)
            b[nt] = *reinterpret_cast<const bf16x8*>(Wt + (nbase + nt * 16 + l15) * 256 + krow);
#pragma unroll
        for (int mt = 0; mt < 4; ++mt)
#pragma unroll
            for (int nt = 0; nt < 4; ++nt)
                acc[mt][nt] = __builtin_amdgcn_mfma_f32_16x16x32_bf16(
                    a[mt], b[nt], acc[mt][nt], 0, 0, 0);
        if (wid == 0) {
            bf16x8 bh = *reinterpret_cast<const bf16x8*>(M2t_hi + l15 * 256 + krow);
            bf16x8 bl = *reinterpret_cast<const bf16x8*>(M2t_lo + l15 * 256 + krow);
#pragma unroll
            for (int mt = 0; mt < 4; ++mt) {
                acce[mt] = __builtin_amdgcn_mfma_f32_16x16x32_bf16(a[mt], bh, acce[mt], 0, 0, 0);
                acce[mt] = __builtin_amdgcn_mfma_f32_16x16x32_bf16(a[mt], bl, acce[mt], 0, 0, 0);
            }
        }
    }

    // C/D layout: col = lane&15, row = (lane>>4)*4 + reg  [verified m89/m91]
#pragma unroll
    for (int mt = 0; mt < 4; ++mt) {
#pragma unroll
        for (int r = 0; r < 4; ++r) {
            int row = mbase + mt * 16 + quad * 4 + r;
            if (row < N_NODES) {
#pragma unroll
                for (int nt = 0; nt < 4; ++nt)
                    ft[(size_t)row * 256 + nbase + nt * 16 + l15] = f2b(acc[mt][nt][r]);
            }
        }
    }
    if (wid == 0) {
#pragma unroll
        for (int mt = 0; mt < 4; ++mt) {
#pragma unroll
            for (int r = 0; r < 4; ++r) {
                int row = mbase + mt * 16 + quad * 4 + r;
                if (row < N_NODES) {
                    float v = acce[mt][r];
                    if (l15 < 8) el[row * 8 + l15] = v;
                    else         er[row * 8 + (l15 - 8)] = v;
                }
            }
        }
    }
}

// ------------------------------------------------------- CSR build
__global__ __launch_bounds__(256) void count_deg(
    const int* __restrict__ dst, int* __restrict__ cnt) {
    int t = blockIdx.x * 256 + threadIdx.x;
    if (t < N_EDGES) atomicAdd(&cnt[dst[t]], 1);
}

__global__ __launch_bounds__(256) void block_sum(
    const int* __restrict__ cnt, int* __restrict__ bsum) {
    int i = blockIdx.x * 256 + threadIdx.x;
    int v = cnt[i];
#pragma unroll
    for (int off = 1; off < 64; off <<= 1) v += __shfl_xor(v, off);
    __shared__ int s[4];
    if ((threadIdx.x & 63) == 0) s[threadIdx.x >> 6] = v;
    __syncthreads();
    if (threadIdx.x == 0) bsum[blockIdx.x] = s[0] + s[1] + s[2] + s[3];
}

__global__ __launch_bounds__(256) void block_scan(
    const int* __restrict__ bsum, int* __restrict__ boff) {
    __shared__ int s[256];
    int t = threadIdx.x;
    int v = (t < 196) ? bsum[t] : 0;
    s[t] = v;
    __syncthreads();
    for (int off = 1; off < 256; off <<= 1) {
        int add = (t >= off) ? s[t - off] : 0;
        __syncthreads();
        s[t] += add;
        __syncthreads();
    }
    if (t < 196) boff[t] = s[t] - v;   // exclusive
}

__global__ __launch_bounds__(256) void scan_offsets(
    const int* __restrict__ cnt, const int* __restrict__ boff,
    int* __restrict__ off, int* __restrict__ cursor) {
    int t = threadIdx.x, lane = t & 63, wid = t >> 6;
    int i = blockIdx.x * 256 + t;
    int c = cnt[i];
    int x = c;
#pragma unroll
    for (int d = 1; d < 64; d <<= 1) {
        int y = __shfl_up(x, d);
        if (lane >= d) x += y;
    }
    __shared__ int wt[4];
    if (lane == 63) wt[wid] = x;
    __syncthreads();
    int woff = 0;
    for (int w = 0; w < wid; ++w) woff += wt[w];
    int excl = boff[blockIdx.x] + woff + x - c;
    off[i] = excl;
    cursor[i] = excl;
}

__global__ __launch_bounds__(256) void bucket_edges(
    const int* __restrict__ src, const int* __restrict__ dst,
    int* __restrict__ cursor, int* __restrict__ inedge_src) {
    int t = blockIdx.x * 256 + threadIdx.x;
    if (t < N_EDGES) {
        int d = dst[t];
        int p = atomicAdd(&cursor[d], 1);
        inedge_src[p] = src[t];
    }
}

// ------------------------------------------------------- aggregation v2
// One wave per dst node. Phase B stashes exp weights in LDS (removes el-gather
// and exp from phase C's chain); phase C unrolled x4 for 4 ft-rows in flight.
// Softmax without max-subtraction (|logit| ~ O(1); mathematically identical).
__global__ __launch_bounds__(256) void aggregate(
    const unsigned short* __restrict__ ft,
    const float* __restrict__ el, const float* __restrict__ er,
    const int* __restrict__ off, const int* __restrict__ cnt,
    const int* __restrict__ inedge_src,
    const float* __restrict__ bias,
    float* __restrict__ out) {
    __shared__ float sexp[4][MAXD * 8];   // 12 KB/block
    int wid = threadIdx.x >> 6, lane = threadIdx.x & 63;
    int v = blockIdx.x * 4 + wid;          // grid exact: v < N always
    int start = off[v], deg = cnt[v];
    int h1 = lane & 7;    // phase B: lane = (edge_local<<3) | head
    int h2 = lane >> 3;   // phase C: lane owns out elems [lane*4, lane*4+4)
    float er1 = er[v * 8 + h1];
    float* my = sexp[wid];
    const int* ip = inedge_src + start;

    // Phase B: per-edge-per-head exp weights -> LDS; denom per head
    float s = 0.f;
    int eidx = lane >> 3;
    for (int base = 0; base < deg; base += 8) {
        int e = base + eidx;
        if (e < deg) {
            int u = ip[e];
            float x = el[u * 8 + h1] + er1;
            x = x > 0.f ? x : 0.2f * x;
            float w = __expf(x);
            if (e < MAXD) my[e * 8 + h1] = w;
            s += w;
        }
    }
    s += __shfl_xor(s, 8);
    s += __shfl_xor(s, 16);
    s += __shfl_xor(s, 32);
    float inv = deg > 0 ? 1.0f / __shfl(s, h2) : 0.f;
    __syncthreads();

    // Phase C: weighted gather-sum, unrolled x4 (raw weights; *inv at end)
    float a0 = 0.f, a1 = 0.f, a2 = 0.f, a3 = 0.f;
    const us4* ftv = reinterpret_cast<const us4*>(ft);
    int mind = deg < MAXD ? deg : MAXD;
    int j = 0;
    for (; j + 4 <= mind; j += 4) {
        int u0 = ip[j], u1 = ip[j + 1], u2 = ip[j + 2], u3 = ip[j + 3];
        us4 f0 = ftv[(size_t)u0 * 64 + lane];
        us4 f1 = ftv[(size_t)u1 * 64 + lane];
        us4 f2 = ftv[(size_t)u2 * 64 + lane];
        us4 f3 = ftv[(size_t)u3 * 64 + lane];
        float w0 = my[(j + 0) * 8 + h2];
        float w1 = my[(j + 1) * 8 + h2];
        float w2 = my[(j + 2) * 8 + h2];
        float w3 = my[(j + 3) * 8 + h2];
        a0 += w0 * b2f(f0.x) + w1 * b2f(f1.x) + w2 * b2f(f2.x) + w3 * b2f(f3.x);
        a1 += w0 * b2f(f0.y) + w1 * b2f(f1.y) + w2 * b2f(f2.y) + w3 * b2f(f3.y);
        a2 += w0 * b2f(f0.z) + w1 * b2f(f1.z) + w2 * b2f(f2.z) + w3 * b2f(f3.z);
        a3 += w0 * b2f(f0.w) + w1 * b2f(f1.w) + w2 * b2f(f2.w) + w3 * b2f(f3.w);
    }
    for (; j < mind; ++j) {
        int u = ip[j];
        us4 f = ftv[(size_t)u * 64 + lane];
        float w = my[j * 8 + h2];
        a0 += w * b2f(f.x); a1 += w * b2f(f.y);
        a2 += w * b2f(f.z); a3 += w * b2f(f.w);
    }
    if (deg > MAXD) {   // overflow fallback (recompute exp)
        float er2 = er[v * 8 + h2];
        for (; j < deg; ++j) {
            int u = ip[j];
            float x = el[u * 8 + h2] + er2;
            x = x > 0.f ? x : 0.2f * x;
            float w = __expf(x);
            us4 f = ftv[(size_t)u * 64 + lane];
            a0 += w * b2f(f.x); a1 += w * b2f(f.y);
            a2 += w * b2f(f.z); a3 += w * b2f(f.w);
        }
    }
    float4 bb = reinterpret_cast<const float4*>(bias)[lane];
    float4 o;
    o.x = a0 * inv + bb.x; o.y = a1 * inv + bb.y;
    o.z = a2 * inv + bb.z; o.w = a3 * inv + bb.w;
    reinterpret_cast<float4*>(out)[(size_t)v * 64 + lane] = o;
}

// ------------------------------------------------------- launch
extern "C" void kernel_launch(void* const* d_in, const int* in_sizes, int n_in,
                              void* d_out, int out_size, void* d_ws, size_t ws_size,
                              hipStream_t stream) {
    const float* feat   = (const float*)d_in[0];
    const float* W      = (const float*)d_in[1];
    const float* attn_l = (const float*)d_in[2];
    const float* attn_r = (const float*)d_in[3];
    const float* bias   = (const float*)d_in[4];
    const int* src = (const int*)d_in[5];
    const int* dst = (const int*)d_in[6];
    float* out = (float*)d_out;

    char* ws = (char*)d_ws;
    // workspace layout (16B aligned), ~32.8 MB total
    unsigned short* Wt     = (unsigned short*)(ws + 0);          //    131,072
    unsigned short* M2t_hi = (unsigned short*)(ws + 131072);     //      8,192
    unsigned short* M2t_lo = (unsigned short*)(ws + 139264);     //      8,192
    unsigned short* ft     = (unsigned short*)(ws + 147456);     // 25,600,000
    float* el              = (float*)(ws + 25747456);            //  1,600,000
    float* er              = (float*)(ws + 27347456);            //  1,600,000
    int* cnt               = (int*)(ws + 28947456);              //    200,704
    int* off               = (int*)(ws + 29148160);              //    200,704
    int* cursor            = (int*)(ws + 29348864);              //    200,704
    int* bsum              = (int*)(ws + 29549568);              //      1,024
    int* boff              = (int*)(ws + 29550592);              //      1,024
    int* inedge_src        = (int*)(ws + 29551616);              //  3,200,000

    hipMemsetAsync(cnt, 0, NPAD * sizeof(int), stream);

    transpose_w<<<256, 256, 0, stream>>>(W, Wt);
    prep_m2<<<16, 256, 0, stream>>>(W, attn_l, attn_r, M2t_hi, M2t_lo);
    gemm_ft<<<782, 256, 0, stream>>>(feat, Wt, M2t_hi, M2t_lo, ft, el, er);
    count_deg<<<3125, 256, 0, stream>>>(dst, cnt);
    block_sum<<<196, 256, 0, stream>>>(cnt, bsum);
    block_scan<<<1, 256, 0, stream>>>(bsum, boff);
    scan_offsets<<<196, 256, 0, stream>>>(cnt, boff, off, cursor);
    bucket_edges<<<3125, 256, 0, stream>>>(src, dst, cursor, inedge_src);
    aggregate<<<12500, 256, 0, stream>>>(ft, el, er, off, cnt, inedge_src, bias, out);
}